// Round 1
// baseline (657.777 us; speedup 1.0000x reference)
//
#include <hip/hip_runtime.h>

typedef __bf16 bf16;
typedef __bf16 bf16x8 __attribute__((ext_vector_type(8)));
typedef __bf16 bf16x4 __attribute__((ext_vector_type(4)));
typedef float f32x4 __attribute__((ext_vector_type(4)));
typedef unsigned int u32;
typedef unsigned short u16;

#define MFMA_BF16 __builtin_amdgcn_mfma_f32_16x16x32_bf16

#define GLOAD_LDS(g, l)                                        \
  __builtin_amdgcn_global_load_lds(                            \
      (__attribute__((address_space(1))) void*)(g),            \
      (__attribute__((address_space(3))) void*)(l), 16, 0, 0)

// ---------------------------------------------------------------- utilities
__global__ void cvt_f32_bf16(const float* __restrict__ in, bf16* __restrict__ out, int n) {
  int i = (blockIdx.x * blockDim.x + threadIdx.x) * 4;
  if (i >= n) return;
  float4 v = *(const float4*)(in + i);
  bf16x4 o;
  o[0] = (bf16)v.x; o[1] = (bf16)v.y; o[2] = (bf16)v.z; o[3] = (bf16)v.w;
  *(bf16x4*)(out + i) = o;
}

// W [K][N] fp32 -> Wt [N][K] bf16
__global__ void transpose_w(const float* __restrict__ w, bf16* __restrict__ wt, int K, int N) {
  __shared__ float tile[32][33];
  int n0 = blockIdx.x * 32, k0 = blockIdx.y * 32;
  int t = threadIdx.x;
  int c = t & 31, r = t >> 5;  // c: 0..31, r: 0..7
#pragma unroll
  for (int i = 0; i < 4; i++)
    tile[r + i * 8][c] = w[(size_t)(k0 + r + i * 8) * N + n0 + c];
  __syncthreads();
#pragma unroll
  for (int i = 0; i < 4; i++)
    wt[(size_t)(n0 + r + i * 8) * K + k0 + c] = (bf16)tile[c][r + i * 8];
}

__device__ inline float gelu_exact(float x) {
  return 0.5f * x * (1.0f + erff(x * 0.70710678118654752f));
}

__device__ inline u32 pack2(float a, float b) {
  u16 ua = __builtin_bit_cast(u16, (bf16)a);
  u16 ub = __builtin_bit_cast(u16, (bf16)b);
  return ((u32)ub << 16) | ua;
}

// ---------------------------------------------------------------- GEMM
// C[M][N] = A[M][K] * Bt[N][K]^T, M=8192, 128x128 tile, BK=32, 4 waves.
// MODE 0: outb = bf16(C)                        (qkv)
// MODE 1: x = C + resid; outf = x; outb = bf16  (attn proj + residual)
// MODE 2: outb = bf16(gelu(C))                  (ff1)
// MODE 3: outf = C + resid                      (ff2 + residual -> d_out)
template <int MODE>
__global__ __launch_bounds__(256) void gemm_bt(
    const bf16* __restrict__ A, const bf16* __restrict__ Bt,
    bf16* __restrict__ outb, float* __restrict__ outf,
    const float* __restrict__ resid, int K, int N) {
  __shared__ __align__(16) bf16 As[128 * 32];
  __shared__ __align__(16) bf16 Bs[128 * 32];
  const int tid = threadIdx.x;
  const int lane = tid & 63, w = tid >> 6;
  const int g = lane >> 4, l15 = lane & 15;
  const int m0 = blockIdx.y * 128, n0 = blockIdx.x * 128;
  const int wm = w >> 1, wn = w & 1;

  f32x4 acc[4][4] = {};

  // staging: wave w, issue i covers rows i*64 + w*16 + lane/4, 64B per row
  const int srow = w * 16 + (lane >> 2);
  const int scolb = (lane & 3) * 16;
  const char* gA = (const char*)A;
  const char* gB = (const char*)Bt;
  const size_t gA0 = ((size_t)(m0 + srow) * K) * 2 + scolb;
  const size_t gA1 = ((size_t)(m0 + 64 + srow) * K) * 2 + scolb;
  const size_t gB0 = ((size_t)(n0 + srow) * K) * 2 + scolb;
  const size_t gB1 = ((size_t)(n0 + 64 + srow) * K) * 2 + scolb;
  bf16* lA0 = &As[w * 512];
  bf16* lA1 = &As[2048 + w * 512];
  bf16* lB0 = &Bs[w * 512];
  bf16* lB1 = &Bs[2048 + w * 512];

  const bf16* pA = &As[(wm * 64 + l15) * 32 + 8 * g];
  const bf16* pB = &Bs[(wn * 64 + l15) * 32 + 8 * g];

  for (int k0 = 0; k0 < K; k0 += 32) {
    const size_t kb = (size_t)k0 * 2;
    GLOAD_LDS(gA + gA0 + kb, lA0);
    GLOAD_LDS(gA + gA1 + kb, lA1);
    GLOAD_LDS(gB + gB0 + kb, lB0);
    GLOAD_LDS(gB + gB1 + kb, lB1);
    __syncthreads();
    bf16x8 af[4], bfr[4];
#pragma unroll
    for (int mi = 0; mi < 4; mi++) af[mi] = *(const bf16x8*)(pA + mi * 16 * 32);
#pragma unroll
    for (int ni = 0; ni < 4; ni++) bfr[ni] = *(const bf16x8*)(pB + ni * 16 * 32);
#pragma unroll
    for (int mi = 0; mi < 4; mi++)
#pragma unroll
      for (int ni = 0; ni < 4; ni++)
        acc[mi][ni] = MFMA_BF16(af[mi], bfr[ni], acc[mi][ni], 0, 0, 0);
    __syncthreads();
  }

  const int row_base = m0 + wm * 64;
  const int col_base = n0 + wn * 64 + l15;
#pragma unroll
  for (int mi = 0; mi < 4; mi++)
#pragma unroll
    for (int ni = 0; ni < 4; ni++) {
      const int c = col_base + ni * 16;
#pragma unroll
      for (int r = 0; r < 4; r++) {
        const int row = row_base + mi * 16 + 4 * g + r;
        const size_t idx = (size_t)row * N + c;
        float v = acc[mi][ni][r];
        if constexpr (MODE == 0) {
          outb[idx] = (bf16)v;
        } else if constexpr (MODE == 1) {
          float xv = v + resid[idx];
          outf[idx] = xv;
          outb[idx] = (bf16)xv;
        } else if constexpr (MODE == 2) {
          outb[idx] = (bf16)gelu_exact(v);
        } else {
          outf[idx] = v + resid[idx];
        }
      }
    }
}

// ---------------------------------------------------------------- attention
// qkv: [B*T][3072] bf16 (cols: [3][16 heads][64]); O: [B*T][1024] bf16.
// Block: 4 waves; wave w owns q-rows [q0+16w, q0+16w+16); KV tiles of 32.
// Swapped QK^T: st = mfma(Kfrag, Qfrag) -> S^T[k][q] (row=k=4g+r, col=q=l15).
__global__ __launch_bounds__(256) void attn_fwd(const bf16* __restrict__ qkv,
                                                bf16* __restrict__ O) {
  __shared__ __align__(16) bf16 Vt[64 * 32];  // [d][k'] transposed V tile
  const int tid = threadIdx.x;
  const int lane = tid & 63, w = tid >> 6;
  const int g = lane >> 4, l15 = lane & 15;
  const int q0 = blockIdx.x * 64;
  const int bh = blockIdx.y;
  const int b = bh >> 4, h = bh & 15;
  const size_t tokbase = (size_t)b * 2048;
  const int qw0 = q0 + w * 16;
  const int qi = qw0 + l15;

  const bf16* qptr = qkv + (tokbase + qw0 + l15) * 3072 + h * 64 + 8 * g;
  bf16x8 qf0 = *(const bf16x8*)(qptr);
  bf16x8 qf1 = *(const bf16x8*)(qptr + 32);

  f32x4 ot[4] = {};
  float m_i = -INFINITY, l_i = 0.0f;

  const int sk = tid >> 3;        // 0..31 : k' row staged by this thread
  const int sd = (tid & 7) * 8;   // 0..56 : d offset
  const bf16* vbase = qkv + tokbase * 3072 + 2048 + h * 64;
  const int kend = q0 + 64;

  for (int k0 = 0; k0 < kend; k0 += 32) {
    // stage V^T tile [64 d][32 k']
    uint4 vv = *(const uint4*)(vbase + (size_t)(k0 + sk) * 3072 + sd);
    const u16* vu = (const u16*)&vv;
    __syncthreads();  // previous iteration's Vt reads done
#pragma unroll
    for (int j = 0; j < 8; j++) ((u16*)Vt)[(sd + j) * 32 + sk] = vu[j];
    __syncthreads();

    if (k0 <= qw0 + 15) {  // wave-uniform causal skip
      const bf16* kptr = qkv + (tokbase + k0 + l15) * 3072 + 1024 + h * 64 + 8 * g;
      bf16x8 kf00 = *(const bf16x8*)(kptr);
      bf16x8 kf01 = *(const bf16x8*)(kptr + 32);
      bf16x8 kf10 = *(const bf16x8*)(kptr + 16 * 3072);
      bf16x8 kf11 = *(const bf16x8*)(kptr + 16 * 3072 + 32);
      f32x4 st0 = {}, st1 = {};
      st0 = MFMA_BF16(kf00, qf0, st0, 0, 0, 0);
      st0 = MFMA_BF16(kf01, qf1, st0, 0, 0, 0);
      st1 = MFMA_BF16(kf10, qf0, st1, 0, 0, 0);
      st1 = MFMA_BF16(kf11, qf1, st1, 0, 0, 0);

      float p[8];
      float mt = -INFINITY;
#pragma unroll
      for (int r = 0; r < 4; r++) {
        int k_lo = k0 + 4 * g + r;
        float v0 = (k_lo <= qi) ? st0[r] * 0.125f : -INFINITY;
        float v1 = (k_lo + 16 <= qi) ? st1[r] * 0.125f : -INFINITY;
        p[r] = v0;
        p[4 + r] = v1;
        mt = fmaxf(mt, fmaxf(v0, v1));
      }
      // reduce across the 4 lane-groups holding the same q column
      mt = fmaxf(mt, __shfl_xor(mt, 16, 64));
      mt = fmaxf(mt, __shfl_xor(mt, 32, 64));
      float m_new = fmaxf(m_i, mt);
      float alpha = __expf(m_i - m_new);
      float s = 0.0f;
#pragma unroll
      for (int j = 0; j < 8; j++) {
        p[j] = __expf(p[j] - m_new);
        s += p[j];
      }
      s += __shfl_xor(s, 16, 64);
      s += __shfl_xor(s, 32, 64);
      l_i = l_i * alpha + s;
      m_i = m_new;
#pragma unroll
      for (int dt = 0; dt < 4; dt++)
#pragma unroll
        for (int r = 0; r < 4; r++) ot[dt][r] *= alpha;

      // pack P^T (bf16) and redistribute D-layout -> B-fragment layout
      u32 pw[4];
      pw[0] = pack2(p[0], p[1]);
      pw[1] = pack2(p[2], p[3]);
      pw[2] = pack2(p[4], p[5]);
      pw[3] = pack2(p[6], p[7]);
      union { u32 w4[4]; bf16x8 v; } bu;
#pragma unroll
      for (int wd = 0; wd < 4; wd++) {
        int sg = 2 * (g & 1) + (wd >> 1);
        int src = sg * 16 + l15;
        int a0 = __shfl((int)pw[wd & 1], src, 64);
        int a1 = __shfl((int)pw[2 + (wd & 1)], src, 64);
        bu.w4[wd] = (u32)((g >= 2) ? a1 : a0);
      }
#pragma unroll
      for (int dt = 0; dt < 4; dt++) {
        bf16x8 vf = *(const bf16x8*)(&Vt[(dt * 16 + l15) * 32 + 8 * g]);
        ot[dt] = MFMA_BF16(vf, bu.v, ot[dt], 0, 0, 0);  // O^T[d][q]
      }
    }
  }

  float inv = 1.0f / l_i;
  bf16* obase = O + (tokbase + qw0 + l15) * 1024 + h * 64;
#pragma unroll
  for (int dt = 0; dt < 4; dt++) {
    bf16x4 ov;
#pragma unroll
    for (int r = 0; r < 4; r++) ov[r] = (bf16)(ot[dt][r] * inv);
    *(bf16x4*)(obase + dt * 16 + 4 * g) = ov;
  }
}

// ---------------------------------------------------------------- launch
extern "C" void kernel_launch(void* const* d_in, const int* in_sizes, int n_in,
                              void* d_out, int out_size, void* d_ws, size_t ws_size,
                              hipStream_t stream) {
  const float* x = (const float*)d_in[0];
  const float* w_qkv = (const float*)d_in[1];
  const float* w_out = (const float*)d_in[2];
  const float* w_ff1 = (const float*)d_in[3];
  const float* w_ff2 = (const float*)d_in[4];
  float* out = (float*)d_out;

  char* ws = (char*)d_ws;
  size_t off = 0;
  auto alloc = [&](size_t bytes) {
    void* p = ws + off;
    off += (bytes + 255) & ~(size_t)255;
    return p;
  };
  const size_t M = 8192;
  bf16* X16   = (bf16*)alloc(M * 1024 * 2);
  bf16* WqkvT = (bf16*)alloc(3072ull * 1024 * 2);
  bf16* WoutT = (bf16*)alloc(1024ull * 1024 * 2);
  bf16* Wff1T = (bf16*)alloc(4096ull * 1024 * 2);
  bf16* Wff2T = (bf16*)alloc(1024ull * 4096 * 2);
  bf16* QKV   = (bf16*)alloc(M * 3072 * 2);
  bf16* Obuf  = (bf16*)alloc(M * 1024 * 2);
  float* x1   = (float*)alloc(M * 1024 * 4);
  bf16* x1b   = (bf16*)alloc(M * 1024 * 2);
  bf16* Hbuf  = (bf16*)alloc(M * 4096 * 2);

  cvt_f32_bf16<<<8192, 256, 0, stream>>>(x, X16, 8192 * 1024);
  transpose_w<<<dim3(3072 / 32, 1024 / 32), 256, 0, stream>>>(w_qkv, WqkvT, 1024, 3072);
  transpose_w<<<dim3(1024 / 32, 1024 / 32), 256, 0, stream>>>(w_out, WoutT, 1024, 1024);
  transpose_w<<<dim3(4096 / 32, 1024 / 32), 256, 0, stream>>>(w_ff1, Wff1T, 1024, 4096);
  transpose_w<<<dim3(1024 / 32, 4096 / 32), 256, 0, stream>>>(w_ff2, Wff2T, 4096, 1024);

  // qkv = X16 @ Wqkv  -> [M][3072] bf16
  gemm_bt<0><<<dim3(3072 / 128, 8192 / 128), 256, 0, stream>>>(
      X16, WqkvT, QKV, nullptr, nullptr, 1024, 3072);
  // causal flash attention -> Obuf [M][1024] bf16
  attn_fwd<<<dim3(2048 / 64, 64), 256, 0, stream>>>(QKV, Obuf);
  // x1 = x + Obuf @ Wout  (fp32 + bf16 copies)
  gemm_bt<1><<<dim3(1024 / 128, 8192 / 128), 256, 0, stream>>>(
      Obuf, WoutT, x1b, x1, x, 1024, 1024);
  // H = gelu(x1 @ Wff1)  -> bf16
  gemm_bt<2><<<dim3(4096 / 128, 8192 / 128), 256, 0, stream>>>(
      x1b, Wff1T, Hbuf, nullptr, nullptr, 1024, 4096);
  // out = x1 + H @ Wff2  -> fp32 d_out
  gemm_bt<3><<<dim3(1024 / 128, 8192 / 128), 256, 0, stream>>>(
      Hbuf, Wff2T, nullptr, out, x1, 4096, 1024);
}

// Round 2
// 649.405 us; speedup vs baseline: 1.0129x; 1.0129x over previous
//
#include <hip/hip_runtime.h>

typedef __bf16 bf16;
typedef __bf16 bf16x8 __attribute__((ext_vector_type(8)));
typedef __bf16 bf16x4 __attribute__((ext_vector_type(4)));
typedef float f32x4 __attribute__((ext_vector_type(4)));
typedef unsigned int u32;
typedef unsigned short u16;

#define MFMA_BF16 __builtin_amdgcn_mfma_f32_16x16x32_bf16

#define GLOAD_LDS(g, l)                                        \
  __builtin_amdgcn_global_load_lds(                            \
      (__attribute__((address_space(1))) void*)(g),            \
      (__attribute__((address_space(3))) void*)(l), 16, 0, 0)

// ---------------------------------------------------------------- utilities
__global__ void cvt_f32_bf16(const float* __restrict__ in, bf16* __restrict__ out, int n) {
  int i = (blockIdx.x * blockDim.x + threadIdx.x) * 4;
  if (i >= n) return;
  float4 v = *(const float4*)(in + i);
  bf16x4 o;
  o[0] = (bf16)v.x; o[1] = (bf16)v.y; o[2] = (bf16)v.z; o[3] = (bf16)v.w;
  *(bf16x4*)(out + i) = o;
}

// W [K][N] fp32 -> Wt [N][K] bf16
__global__ void transpose_w(const float* __restrict__ w, bf16* __restrict__ wt, int K, int N) {
  __shared__ float tile[32][33];
  int n0 = blockIdx.x * 32, k0 = blockIdx.y * 32;
  int t = threadIdx.x;
  int c = t & 31, r = t >> 5;
#pragma unroll
  for (int i = 0; i < 4; i++)
    tile[r + i * 8][c] = w[(size_t)(k0 + r + i * 8) * N + n0 + c];
  __syncthreads();
#pragma unroll
  for (int i = 0; i < 4; i++)
    wt[(size_t)(n0 + r + i * 8) * K + k0 + c] = (bf16)tile[c][r + i * 8];
}

__device__ inline float gelu_exact(float x) {
  return 0.5f * x * (1.0f + erff(x * 0.70710678118654752f));
}

// ---------------------------------------------------------------- GEMM
// C[M][N] = A[M][K] * Bt[N][K]^T, M=8192, 128x128 tile, BK=32, 4 waves.
template <int MODE>
__global__ __launch_bounds__(256) void gemm_bt(
    const bf16* __restrict__ A, const bf16* __restrict__ Bt,
    bf16* __restrict__ outb, float* __restrict__ outf,
    const float* __restrict__ resid, int K, int N) {
  __shared__ __align__(16) bf16 As[128 * 32];
  __shared__ __align__(16) bf16 Bs[128 * 32];
  const int tid = threadIdx.x;
  const int lane = tid & 63, w = tid >> 6;
  const int g = lane >> 4, l15 = lane & 15;
  const int m0 = blockIdx.y * 128, n0 = blockIdx.x * 128;
  const int wm = w >> 1, wn = w & 1;

  f32x4 acc[4][4] = {};

  const int srow = w * 16 + (lane >> 2);
  const int scolb = (lane & 3) * 16;
  const char* gA = (const char*)A;
  const char* gB = (const char*)Bt;
  const size_t gA0 = ((size_t)(m0 + srow) * K) * 2 + scolb;
  const size_t gA1 = ((size_t)(m0 + 64 + srow) * K) * 2 + scolb;
  const size_t gB0 = ((size_t)(n0 + srow) * K) * 2 + scolb;
  const size_t gB1 = ((size_t)(n0 + 64 + srow) * K) * 2 + scolb;
  bf16* lA0 = &As[w * 512];
  bf16* lA1 = &As[2048 + w * 512];
  bf16* lB0 = &Bs[w * 512];
  bf16* lB1 = &Bs[2048 + w * 512];

  const bf16* pA = &As[(wm * 64 + l15) * 32 + 8 * g];
  const bf16* pB = &Bs[(wn * 64 + l15) * 32 + 8 * g];

  for (int k0 = 0; k0 < K; k0 += 32) {
    const size_t kb = (size_t)k0 * 2;
    GLOAD_LDS(gA + gA0 + kb, lA0);
    GLOAD_LDS(gA + gA1 + kb, lA1);
    GLOAD_LDS(gB + gB0 + kb, lB0);
    GLOAD_LDS(gB + gB1 + kb, lB1);
    __syncthreads();
    bf16x8 af[4], bfr[4];
#pragma unroll
    for (int mi = 0; mi < 4; mi++) af[mi] = *(const bf16x8*)(pA + mi * 16 * 32);
#pragma unroll
    for (int ni = 0; ni < 4; ni++) bfr[ni] = *(const bf16x8*)(pB + ni * 16 * 32);
#pragma unroll
    for (int mi = 0; mi < 4; mi++)
#pragma unroll
      for (int ni = 0; ni < 4; ni++)
        acc[mi][ni] = MFMA_BF16(af[mi], bfr[ni], acc[mi][ni], 0, 0, 0);
    __syncthreads();
  }

  const int row_base = m0 + wm * 64;
  const int col_base = n0 + wn * 64 + l15;
#pragma unroll
  for (int mi = 0; mi < 4; mi++)
#pragma unroll
    for (int ni = 0; ni < 4; ni++) {
      const int c = col_base + ni * 16;
#pragma unroll
      for (int r = 0; r < 4; r++) {
        const int row = row_base + mi * 16 + 4 * g + r;
        const size_t idx = (size_t)row * N + c;
        float v = acc[mi][ni][r];
        if constexpr (MODE == 0) {
          outb[idx] = (bf16)v;
        } else if constexpr (MODE == 1) {
          float xv = v + resid[idx];
          outf[idx] = xv;
          outb[idx] = (bf16)xv;
        } else if constexpr (MODE == 2) {
          outb[idx] = (bf16)gelu_exact(v);
        } else {
          outf[idx] = v + resid[idx];
        }
      }
    }
}

// ---------------------------------------------------------------- attention
// qkv: [B*T][3072] bf16 (cols: [3][16 heads][64]); O: [B*T][1024] bf16.
// 4 waves; wave w owns q-rows [q0+16w, q0+16w+16); KV tiles of 64.
// QK^T with PERMUTED K rows: acc st[2i+h] loads K rows 32i+8*(l15>>2)+4h+(l15&3),
// so D-layout leaves P directly in the PV x32 B-frag layout (k=32i+8g+4h+r, j=4h+r).
// V^T staged in LDS [64 d][64 k], 16B-slot XOR swizzle slot^=(d>>1)&7.
__global__ __launch_bounds__(256) void attn_fwd(const bf16* __restrict__ qkv,
                                                bf16* __restrict__ O) {
  __shared__ __align__(16) char VtB[64 * 128];  // V^T tile, 8KB
  const int tid = threadIdx.x;
  const int lane = tid & 63, w = tid >> 6;
  const int g = lane >> 4, l15 = lane & 15;
  const int q0 = blockIdx.x * 64;
  const int bh = blockIdx.y;
  const int b = bh >> 4, hh = bh & 15;
  const size_t tokbase = (size_t)b * 2048;
  const int qw0 = q0 + w * 16;
  const int qi = qw0 + l15;

  const bf16* qptr = qkv + (tokbase + qw0 + l15) * 3072 + hh * 64 + 8 * g;
  const bf16x8 qf0 = *(const bf16x8*)(qptr);
  const bf16x8 qf1 = *(const bf16x8*)(qptr + 32);

  f32x4 ot[4] = {};
  float m_i = -INFINITY, l_i = 0.0f;

  // V staging: thread t handles k rows 4*rg..4*rg+3, d cols dseg4..dseg4+3
  const int rg = tid >> 4;
  const int dseg4 = (tid & 15) * 4;
  const bf16* vbase = qkv + tokbase * 3072 + 2048 + hh * 64;
  const bf16* kb0 = qkv + tokbase * 3072 + 1024 + hh * 64 + 8 * g;
  const int kperm = 8 * (l15 >> 2) + (l15 & 3);
  const int kend = q0 + 64;

  for (int k0 = 0; k0 < kend; k0 += 64) {
    // ---- stage V^T tile (in-register 4x4 transpose -> b64 writes)
    union U4 { ushort4 v; u16 a[4]; };
    U4 vr[4];
#pragma unroll
    for (int i4 = 0; i4 < 4; i4++)
      vr[i4].v = *(const ushort4*)(vbase + (size_t)(k0 + 4 * rg + i4) * 3072 + dseg4);
    __syncthreads();  // previous tile's Vt reads done
#pragma unroll
    for (int dj = 0; dj < 4; dj++) {
      const int d = dseg4 + dj;
      u32 lo = (u32)vr[0].a[dj] | ((u32)vr[1].a[dj] << 16);
      u32 hi = (u32)vr[2].a[dj] | ((u32)vr[3].a[dj] << 16);
      const int boff = d * 128 + ((((rg >> 1) ^ ((d >> 1) & 7)) << 4)) + ((rg & 1) << 3);
      *(uint2*)(VtB + boff) = make_uint2(lo, hi);
    }
    __syncthreads();

    const bool lastT = (k0 + 63 > qw0);
    const int npair = lastT ? (((qw0 + 15 - k0) >> 5) + 1) : 2;

    // ---- QK^T (permuted K rows)
    bf16x8 ka[4], kbv[4];
#pragma unroll
    for (int ip = 0; ip < 2; ip++)
      if (ip < npair) {
#pragma unroll
        for (int h2 = 0; h2 < 2; h2++) {
          const int ks = 2 * ip + h2;
          const bf16* kp = kb0 + (size_t)(k0 + 32 * ip + 4 * h2 + kperm) * 3072;
          ka[ks] = *(const bf16x8*)(kp);
          kbv[ks] = *(const bf16x8*)(kp + 32);
        }
      }
    f32x4 st[4];
#pragma unroll
    for (int ip = 0; ip < 2; ip++)
      if (ip < npair) {
#pragma unroll
        for (int h2 = 0; h2 < 2; h2++) {
          const int ks = 2 * ip + h2;
          f32x4 z = {};
          z = MFMA_BF16(ka[ks], qf0, z, 0, 0, 0);
          st[ks] = MFMA_BF16(kbv[ks], qf1, z, 0, 0, 0);
        }
      }

    // ---- softmax (lane holds k = k0 + 32*ip + 8g + 4*h2 + r for column q=l15)
    float p[4][4];
    float mt = -INFINITY;
#pragma unroll
    for (int ip = 0; ip < 2; ip++)
      if (ip < npair) {
#pragma unroll
        for (int h2 = 0; h2 < 2; h2++)
#pragma unroll
          for (int r = 0; r < 4; r++) {
            const int kk = k0 + 32 * ip + 8 * g + 4 * h2 + r;
            float v = (float)st[2 * ip + h2][r] * 0.125f;
            if (lastT && kk > qi) v = -INFINITY;
            p[2 * ip + h2][r] = v;
            mt = fmaxf(mt, v);
          }
      }
    mt = fmaxf(mt, __shfl_xor(mt, 16, 64));
    mt = fmaxf(mt, __shfl_xor(mt, 32, 64));

    if (!__all(mt - m_i <= 8.0f)) {  // defer-max (T13)
      const float m_new = fmaxf(m_i, mt);
      const float alpha = __expf(m_i - m_new);
      l_i *= alpha;
#pragma unroll
      for (int dt = 0; dt < 4; dt++)
#pragma unroll
        for (int r = 0; r < 4; r++) ot[dt][r] *= alpha;
      m_i = m_new;
    }
    float s = 0.0f;
#pragma unroll
    for (int ip = 0; ip < 2; ip++)
      if (ip < npair) {
#pragma unroll
        for (int h2 = 0; h2 < 2; h2++)
#pragma unroll
          for (int r = 0; r < 4; r++) {
            float e = __expf(p[2 * ip + h2][r] - m_i);
            p[2 * ip + h2][r] = e;
            s += e;
          }
      }
    s += __shfl_xor(s, 16, 64);
    s += __shfl_xor(s, 32, 64);
    l_i += s;

    // ---- PV: O^T += V^T * P^T (P already in B-frag layout)
#pragma unroll
    for (int ip = 0; ip < 2; ip++)
      if (ip < npair) {
        bf16x8 pf;
#pragma unroll
        for (int h2 = 0; h2 < 2; h2++)
#pragma unroll
          for (int r = 0; r < 4; r++) pf[4 * h2 + r] = (bf16)p[2 * ip + h2][r];
#pragma unroll
        for (int dt = 0; dt < 4; dt++) {
          const bf16x8 vf = *(const bf16x8*)(
              VtB + (dt * 16 + l15) * 128 + (((4 * ip + g) ^ (l15 >> 1)) << 4));
          ot[dt] = MFMA_BF16(vf, pf, ot[dt], 0, 0, 0);
        }
      }
  }

  const float inv = 1.0f / l_i;
  bf16* obase = O + (tokbase + qw0 + l15) * 1024 + hh * 64;
#pragma unroll
  for (int dt = 0; dt < 4; dt++) {
    bf16x4 ov;
#pragma unroll
    for (int r = 0; r < 4; r++) ov[r] = (bf16)(ot[dt][r] * inv);
    *(bf16x4*)(obase + dt * 16 + 4 * g) = ov;
  }
}

// ---------------------------------------------------------------- launch
extern "C" void kernel_launch(void* const* d_in, const int* in_sizes, int n_in,
                              void* d_out, int out_size, void* d_ws, size_t ws_size,
                              hipStream_t stream) {
  const float* x = (const float*)d_in[0];
  const float* w_qkv = (const float*)d_in[1];
  const float* w_out = (const float*)d_in[2];
  const float* w_ff1 = (const float*)d_in[3];
  const float* w_ff2 = (const float*)d_in[4];
  float* out = (float*)d_out;

  char* ws = (char*)d_ws;
  size_t off = 0;
  auto alloc = [&](size_t bytes) {
    void* p = ws + off;
    off += (bytes + 255) & ~(size_t)255;
    return p;
  };
  const size_t M = 8192;
  bf16* X16   = (bf16*)alloc(M * 1024 * 2);
  bf16* WqkvT = (bf16*)alloc(3072ull * 1024 * 2);
  bf16* WoutT = (bf16*)alloc(1024ull * 1024 * 2);
  bf16* Wff1T = (bf16*)alloc(4096ull * 1024 * 2);
  bf16* Wff2T = (bf16*)alloc(1024ull * 4096 * 2);
  bf16* QKV   = (bf16*)alloc(M * 3072 * 2);
  bf16* Obuf  = (bf16*)alloc(M * 1024 * 2);
  float* x1   = (float*)alloc(M * 1024 * 4);
  bf16* x1b   = (bf16*)alloc(M * 1024 * 2);
  bf16* Hbuf  = (bf16*)alloc(M * 4096 * 2);

  cvt_f32_bf16<<<8192, 256, 0, stream>>>(x, X16, 8192 * 1024);
  transpose_w<<<dim3(3072 / 32, 1024 / 32), 256, 0, stream>>>(w_qkv, WqkvT, 1024, 3072);
  transpose_w<<<dim3(1024 / 32, 1024 / 32), 256, 0, stream>>>(w_out, WoutT, 1024, 1024);
  transpose_w<<<dim3(4096 / 32, 1024 / 32), 256, 0, stream>>>(w_ff1, Wff1T, 1024, 4096);
  transpose_w<<<dim3(1024 / 32, 4096 / 32), 256, 0, stream>>>(w_ff2, Wff2T, 4096, 1024);

  gemm_bt<0><<<dim3(3072 / 128, 8192 / 128), 256, 0, stream>>>(
      X16, WqkvT, QKV, nullptr, nullptr, 1024, 3072);
  attn_fwd<<<dim3(2048 / 64, 64), 256, 0, stream>>>(QKV, Obuf);
  gemm_bt<1><<<dim3(1024 / 128, 8192 / 128), 256, 0, stream>>>(
      Obuf, WoutT, x1b, x1, x, 1024, 1024);
  gemm_bt<2><<<dim3(4096 / 128, 8192 / 128), 256, 0, stream>>>(
      x1b, Wff1T, Hbuf, nullptr, nullptr, 1024, 4096);
  gemm_bt<3><<<dim3(1024 / 128, 8192 / 128), 256, 0, stream>>>(
      Hbuf, Wff2T, nullptr, out, x1, 4096, 1024);
}

// Round 3
// 586.486 us; speedup vs baseline: 1.1216x; 1.1073x over previous
//
#include <hip/hip_runtime.h>

typedef __bf16 bf16;
typedef __bf16 bf16x8 __attribute__((ext_vector_type(8)));
typedef __bf16 bf16x4 __attribute__((ext_vector_type(4)));
typedef float f32x4 __attribute__((ext_vector_type(4)));
typedef unsigned int u32;
typedef unsigned short u16;

#define MFMA_BF16 __builtin_amdgcn_mfma_f32_16x16x32_bf16

#define GLOAD_LDS(g, l)                                        \
  __builtin_amdgcn_global_load_lds(                            \
      (__attribute__((address_space(1))) void*)(g),            \
      (__attribute__((address_space(3))) void*)(l), 16, 0, 0)

// ---------------------------------------------------------------- utilities
__global__ void cvt_f32_bf16(const float* __restrict__ in, bf16* __restrict__ out, int n) {
  int i = (blockIdx.x * blockDim.x + threadIdx.x) * 4;
  if (i >= n) return;
  float4 v = *(const float4*)(in + i);
  bf16x4 o;
  o[0] = (bf16)v.x; o[1] = (bf16)v.y; o[2] = (bf16)v.z; o[3] = (bf16)v.w;
  *(bf16x4*)(out + i) = o;
}

// W [K][N] fp32 -> Wt [N][K] bf16
__global__ void transpose_w(const float* __restrict__ w, bf16* __restrict__ wt, int K, int N) {
  __shared__ float tile[32][33];
  int n0 = blockIdx.x * 32, k0 = blockIdx.y * 32;
  int t = threadIdx.x;
  int c = t & 31, r = t >> 5;
#pragma unroll
  for (int i = 0; i < 4; i++)
    tile[r + i * 8][c] = w[(size_t)(k0 + r + i * 8) * N + n0 + c];
  __syncthreads();
#pragma unroll
  for (int i = 0; i < 4; i++)
    wt[(size_t)(n0 + r + i * 8) * K + k0 + c] = (bf16)tile[c][r + i * 8];
}

__device__ inline float gelu_exact(float x) {
  return 0.5f * x * (1.0f + erff(x * 0.70710678118654752f));
}

// ---------------------------------------------------------------- GEMM
// C[M][N] = A[M][K] * Bt[N][K]^T, M=8192, 128x128 tile, BK=32, 4 waves.
template <int MODE>
__global__ __launch_bounds__(256) void gemm_bt(
    const bf16* __restrict__ A, const bf16* __restrict__ Bt,
    bf16* __restrict__ outb, float* __restrict__ outf,
    const float* __restrict__ resid, int K, int N) {
  __shared__ __align__(16) bf16 As[128 * 32];
  __shared__ __align__(16) bf16 Bs[128 * 32];
  const int tid = threadIdx.x;
  const int lane = tid & 63, w = tid >> 6;
  const int g = lane >> 4, l15 = lane & 15;
  const int m0 = blockIdx.y * 128, n0 = blockIdx.x * 128;
  const int wm = w >> 1, wn = w & 1;

  f32x4 acc[4][4] = {};

  const int srow = w * 16 + (lane >> 2);
  const int scolb = (lane & 3) * 16;
  const char* gA = (const char*)A;
  const char* gB = (const char*)Bt;
  const size_t gA0 = ((size_t)(m0 + srow) * K) * 2 + scolb;
  const size_t gA1 = ((size_t)(m0 + 64 + srow) * K) * 2 + scolb;
  const size_t gB0 = ((size_t)(n0 + srow) * K) * 2 + scolb;
  const size_t gB1 = ((size_t)(n0 + 64 + srow) * K) * 2 + scolb;
  bf16* lA0 = &As[w * 512];
  bf16* lA1 = &As[2048 + w * 512];
  bf16* lB0 = &Bs[w * 512];
  bf16* lB1 = &Bs[2048 + w * 512];

  const bf16* pA = &As[(wm * 64 + l15) * 32 + 8 * g];
  const bf16* pB = &Bs[(wn * 64 + l15) * 32 + 8 * g];

  for (int k0 = 0; k0 < K; k0 += 32) {
    const size_t kb = (size_t)k0 * 2;
    GLOAD_LDS(gA + gA0 + kb, lA0);
    GLOAD_LDS(gA + gA1 + kb, lA1);
    GLOAD_LDS(gB + gB0 + kb, lB0);
    GLOAD_LDS(gB + gB1 + kb, lB1);
    __syncthreads();
    bf16x8 af[4], bfr[4];
#pragma unroll
    for (int mi = 0; mi < 4; mi++) af[mi] = *(const bf16x8*)(pA + mi * 16 * 32);
#pragma unroll
    for (int ni = 0; ni < 4; ni++) bfr[ni] = *(const bf16x8*)(pB + ni * 16 * 32);
#pragma unroll
    for (int mi = 0; mi < 4; mi++)
#pragma unroll
      for (int ni = 0; ni < 4; ni++)
        acc[mi][ni] = MFMA_BF16(af[mi], bfr[ni], acc[mi][ni], 0, 0, 0);
    __syncthreads();
  }

  const int row_base = m0 + wm * 64;
  const int col_base = n0 + wn * 64 + l15;
#pragma unroll
  for (int mi = 0; mi < 4; mi++)
#pragma unroll
    for (int ni = 0; ni < 4; ni++) {
      const int c = col_base + ni * 16;
#pragma unroll
      for (int r = 0; r < 4; r++) {
        const int row = row_base + mi * 16 + 4 * g + r;
        const size_t idx = (size_t)row * N + c;
        float v = acc[mi][ni][r];
        if constexpr (MODE == 0) {
          outb[idx] = (bf16)v;
        } else if constexpr (MODE == 1) {
          float xv = v + resid[idx];
          outf[idx] = xv;
          outb[idx] = (bf16)xv;
        } else if constexpr (MODE == 2) {
          outb[idx] = (bf16)gelu_exact(v);
        } else {
          outf[idx] = v + resid[idx];
        }
      }
    }
}

// ---------------------------------------------------------------- attention
// qkv: [B*T][3072] bf16; O: [B*T][1024] bf16.
// Uniform-work pairing: block bx processes q-tiles bx and 31-bx (64 rows each)
// sequentially -> exactly 33 KV-steps per block. 1024 blocks, 4 waves,
// 16 waves/CU. Double-buffered V^T in LDS, ONE barrier per step, V prefetched
// into registers during compute (latency hidden under QK/softmax/PV).
__global__ __launch_bounds__(256, 4) void attn_fwd(const bf16* __restrict__ qkv,
                                                   bf16* __restrict__ O) {
  __shared__ __align__(16) char VtB[2][64 * 128];  // 2 x 8KB V^T tiles
  const int tid = threadIdx.x;
  const int lane = tid & 63, w = tid >> 6;
  const int g = lane >> 4, l15 = lane & 15;
  const int bh = blockIdx.y;
  const int b = bh >> 4, hh = bh & 15;
  const size_t tokbase = (size_t)b * 2048;

  const int rg = tid >> 4;
  const int dseg4 = (tid & 15) * 4;
  const bf16* vbase = qkv + tokbase * 3072 + 2048 + hh * 64;
  const bf16* kb0 = qkv + tokbase * 3072 + 1024 + hh * 64 + 8 * g;
  const int kperm = 8 * (l15 >> 2) + (l15 & 3);

  union U4 { ushort4 v; u16 a[4]; };
  U4 vr[4];
  // prologue: prefetch V tile k0=0 into registers
#pragma unroll
  for (int i4 = 0; i4 < 4; i4++)
    vr[i4].v = *(const ushort4*)(vbase + (size_t)(4 * rg + i4) * 3072 + dseg4);
  int cur = 0;

  for (int half = 0; half < 2; half++) {
    const int xT = half ? (31 - (int)blockIdx.x) : (int)blockIdx.x;
    const int q0 = xT * 64;
    const int qw0 = q0 + 16 * w;
    const int qi = qw0 + l15;
    const int kend = q0 + 64;

    const bf16* qptr = qkv + (tokbase + qw0 + l15) * 3072 + hh * 64 + 8 * g;
    const bf16x8 qf0 = *(const bf16x8*)(qptr);
    const bf16x8 qf1 = *(const bf16x8*)(qptr + 32);

    f32x4 ot[4] = {};
    float m_i = -INFINITY, l_i = 0.0f;

    for (int k0 = 0; k0 < kend; k0 += 64) {
      char* Vcur = VtB[cur];
      // ---- write prefetched V regs -> LDS (in-register 4x4 transpose)
#pragma unroll
      for (int dj = 0; dj < 4; dj++) {
        const int d = dseg4 + dj;
        u32 lo = (u32)vr[0].a[dj] | ((u32)vr[1].a[dj] << 16);
        u32 hi = (u32)vr[2].a[dj] | ((u32)vr[3].a[dj] << 16);
        const int boff = d * 128 + ((((rg >> 1) ^ ((d >> 1) & 7)) << 4)) + ((rg & 1) << 3);
        *(uint2*)(Vcur + boff) = make_uint2(lo, hi);
      }
      __syncthreads();  // single barrier per step (dbuf makes it sufficient)

      // ---- issue next step's V loads (hidden under compute below)
      const int k0n = (k0 + 64 < kend) ? k0 + 64 : 0;  // ==0: next tile's first
#pragma unroll
      for (int i4 = 0; i4 < 4; i4++)
        vr[i4].v = *(const ushort4*)(vbase + (size_t)(k0n + 4 * rg + i4) * 3072 + dseg4);

      if (k0 <= qw0 + 15) {  // wave-uniform causal skip
        const bool lastT = (k0 + 63 > qw0);
        const int npair = lastT ? (((qw0 + 15 - k0) >> 5) + 1) : 2;

        // ---- QK^T (permuted K rows -> P lands in PV B-frag layout)
        bf16x8 ka[4], kbv[4];
#pragma unroll
        for (int ip = 0; ip < 2; ip++)
          if (ip < npair) {
#pragma unroll
            for (int h2 = 0; h2 < 2; h2++) {
              const int ks = 2 * ip + h2;
              const bf16* kp = kb0 + (size_t)(k0 + 32 * ip + 4 * h2 + kperm) * 3072;
              ka[ks] = *(const bf16x8*)(kp);
              kbv[ks] = *(const bf16x8*)(kp + 32);
            }
          }
        f32x4 st[4];
#pragma unroll
        for (int ip = 0; ip < 2; ip++)
          if (ip < npair) {
#pragma unroll
            for (int h2 = 0; h2 < 2; h2++) {
              const int ks = 2 * ip + h2;
              f32x4 z = {};
              z = MFMA_BF16(ka[ks], qf0, z, 0, 0, 0);
              st[ks] = MFMA_BF16(kbv[ks], qf1, z, 0, 0, 0);
            }
          }

        // ---- softmax: lane holds k = k0 + 32*ip + 8g + 4*h2 + r, col q=l15
        float p[4][4];
        float mt = -INFINITY;
#pragma unroll
        for (int ip = 0; ip < 2; ip++)
          if (ip < npair) {
#pragma unroll
            for (int h2 = 0; h2 < 2; h2++)
#pragma unroll
              for (int r = 0; r < 4; r++) {
                const int kk = k0 + 32 * ip + 8 * g + 4 * h2 + r;
                float v = (float)st[2 * ip + h2][r] * 0.125f;
                if (lastT && kk > qi) v = -INFINITY;
                p[2 * ip + h2][r] = v;
                mt = fmaxf(mt, v);
              }
          }
        mt = fmaxf(mt, __shfl_xor(mt, 16, 64));
        mt = fmaxf(mt, __shfl_xor(mt, 32, 64));

        if (!__all(mt - m_i <= 8.0f)) {  // defer-max (T13)
          const float m_new = fmaxf(m_i, mt);
          const float alpha = __expf(m_i - m_new);
          l_i *= alpha;
#pragma unroll
          for (int dt = 0; dt < 4; dt++)
#pragma unroll
            for (int r = 0; r < 4; r++) ot[dt][r] *= alpha;
          m_i = m_new;
        }
        float s = 0.0f;
#pragma unroll
        for (int ip = 0; ip < 2; ip++)
          if (ip < npair) {
#pragma unroll
            for (int h2 = 0; h2 < 2; h2++)
#pragma unroll
              for (int r = 0; r < 4; r++) {
                float e = __expf(p[2 * ip + h2][r] - m_i);
                p[2 * ip + h2][r] = e;
                s += e;
              }
          }
        s += __shfl_xor(s, 16, 64);
        s += __shfl_xor(s, 32, 64);
        l_i += s;

        // ---- PV: O^T += V^T * P^T
#pragma unroll
        for (int ip = 0; ip < 2; ip++)
          if (ip < npair) {
            bf16x8 pf;
#pragma unroll
            for (int h2 = 0; h2 < 2; h2++)
#pragma unroll
              for (int r = 0; r < 4; r++) pf[4 * h2 + r] = (bf16)p[2 * ip + h2][r];
#pragma unroll
            for (int dt = 0; dt < 4; dt++) {
              const bf16x8 vf = *(const bf16x8*)(
                  Vcur + (dt * 16 + l15) * 128 + (((4 * ip + g) ^ (l15 >> 1)) << 4));
              ot[dt] = MFMA_BF16(vf, pf, ot[dt], 0, 0, 0);
            }
          }
      }
      cur ^= 1;
    }

    const float inv = 1.0f / l_i;
    bf16* obase = O + (tokbase + qw0 + l15) * 1024 + hh * 64;
#pragma unroll
    for (int dt = 0; dt < 4; dt++) {
      bf16x4 ov;
#pragma unroll
      for (int r = 0; r < 4; r++) ov[r] = (bf16)(ot[dt][r] * inv);
      *(bf16x4*)(obase + dt * 16 + 4 * g) = ov;
    }
  }
}

// ---------------------------------------------------------------- launch
extern "C" void kernel_launch(void* const* d_in, const int* in_sizes, int n_in,
                              void* d_out, int out_size, void* d_ws, size_t ws_size,
                              hipStream_t stream) {
  const float* x = (const float*)d_in[0];
  const float* w_qkv = (const float*)d_in[1];
  const float* w_out = (const float*)d_in[2];
  const float* w_ff1 = (const float*)d_in[3];
  const float* w_ff2 = (const float*)d_in[4];
  float* out = (float*)d_out;

  char* ws = (char*)d_ws;
  size_t off = 0;
  auto alloc = [&](size_t bytes) {
    void* p = ws + off;
    off += (bytes + 255) & ~(size_t)255;
    return p;
  };
  const size_t M = 8192;
  bf16* X16   = (bf16*)alloc(M * 1024 * 2);
  bf16* WqkvT = (bf16*)alloc(3072ull * 1024 * 2);
  bf16* WoutT = (bf16*)alloc(1024ull * 1024 * 2);
  bf16* Wff1T = (bf16*)alloc(4096ull * 1024 * 2);
  bf16* Wff2T = (bf16*)alloc(1024ull * 4096 * 2);
  bf16* QKV   = (bf16*)alloc(M * 3072 * 2);
  bf16* Obuf  = (bf16*)alloc(M * 1024 * 2);
  float* x1   = (float*)alloc(M * 1024 * 4);
  bf16* x1b   = (bf16*)alloc(M * 1024 * 2);
  bf16* Hbuf  = (bf16*)alloc(M * 4096 * 2);

  cvt_f32_bf16<<<8192, 256, 0, stream>>>(x, X16, 8192 * 1024);
  transpose_w<<<dim3(3072 / 32, 1024 / 32), 256, 0, stream>>>(w_qkv, WqkvT, 1024, 3072);
  transpose_w<<<dim3(1024 / 32, 1024 / 32), 256, 0, stream>>>(w_out, WoutT, 1024, 1024);
  transpose_w<<<dim3(4096 / 32, 1024 / 32), 256, 0, stream>>>(w_ff1, Wff1T, 1024, 4096);
  transpose_w<<<dim3(1024 / 32, 4096 / 32), 256, 0, stream>>>(w_ff2, Wff2T, 4096, 1024);

  gemm_bt<0><<<dim3(3072 / 128, 8192 / 128), 256, 0, stream>>>(
      X16, WqkvT, QKV, nullptr, nullptr, 1024, 3072);
  attn_fwd<<<dim3(16, 64), 256, 0, stream>>>(QKV, Obuf);
  gemm_bt<1><<<dim3(1024 / 128, 8192 / 128), 256, 0, stream>>>(
      Obuf, WoutT, x1b, x1, x, 1024, 1024);
  gemm_bt<2><<<dim3(4096 / 128, 8192 / 128), 256, 0, stream>>>(
      x1b, Wff1T, Hbuf, nullptr, nullptr, 1024, 4096);
  gemm_bt<3><<<dim3(1024 / 128, 8192 / 128), 256, 0, stream>>>(
      Hbuf, Wff2T, nullptr, out, x1, 4096, 1024);
}

// Round 4
// 440.915 us; speedup vs baseline: 1.4918x; 1.3302x over previous
//
#include <hip/hip_runtime.h>

typedef __bf16 bf16;
typedef __bf16 bf16x8 __attribute__((ext_vector_type(8)));
typedef __bf16 bf16x4 __attribute__((ext_vector_type(4)));
typedef float f32x4 __attribute__((ext_vector_type(4)));
typedef unsigned int u32;
typedef unsigned short u16;

#define MFMA_BF16 __builtin_amdgcn_mfma_f32_16x16x32_bf16

#define GLOAD_LDS(g, l)                                        \
  __builtin_amdgcn_global_load_lds(                            \
      (__attribute__((address_space(1))) void*)(g),            \
      (__attribute__((address_space(3))) void*)(l), 16, 0, 0)

// ---------------------------------------------------------------- utilities
__global__ void cvt_f32_bf16(const float* __restrict__ in, bf16* __restrict__ out, int n) {
  int i = (blockIdx.x * blockDim.x + threadIdx.x) * 4;
  if (i >= n) return;
  float4 v = *(const float4*)(in + i);
  bf16x4 o;
  o[0] = (bf16)v.x; o[1] = (bf16)v.y; o[2] = (bf16)v.z; o[3] = (bf16)v.w;
  *(bf16x4*)(out + i) = o;
}

// W [K][N] fp32 -> Wt [N][K] bf16
__global__ void transpose_w(const float* __restrict__ w, bf16* __restrict__ wt, int K, int N) {
  __shared__ float tile[32][33];
  int n0 = blockIdx.x * 32, k0 = blockIdx.y * 32;
  int t = threadIdx.x;
  int c = t & 31, r = t >> 5;
#pragma unroll
  for (int i = 0; i < 4; i++)
    tile[r + i * 8][c] = w[(size_t)(k0 + r + i * 8) * N + n0 + c];
  __syncthreads();
#pragma unroll
  for (int i = 0; i < 4; i++)
    wt[(size_t)(n0 + r + i * 8) * K + k0 + c] = (bf16)tile[c][r + i * 8];
}

__device__ inline float gelu_exact(float x) {
  return 0.5f * x * (1.0f + erff(x * 0.70710678118654752f));
}

// ---------------------------------------------------------------- GEMM
// C[M][N] = A[M][K] * Bt[N][K]^T, M=8192, 128x128 tile, BK=32, 4 waves.
template <int MODE>
__global__ __launch_bounds__(256) void gemm_bt(
    const bf16* __restrict__ A, const bf16* __restrict__ Bt,
    bf16* __restrict__ outb, float* __restrict__ outf,
    const float* __restrict__ resid, int K, int N) {
  __shared__ __align__(16) bf16 As[128 * 32];
  __shared__ __align__(16) bf16 Bs[128 * 32];
  const int tid = threadIdx.x;
  const int lane = tid & 63, w = tid >> 6;
  const int g = lane >> 4, l15 = lane & 15;
  const int m0 = blockIdx.y * 128, n0 = blockIdx.x * 128;
  const int wm = w >> 1, wn = w & 1;

  f32x4 acc[4][4] = {};

  const int srow = w * 16 + (lane >> 2);
  const int scolb = (lane & 3) * 16;
  const char* gA = (const char*)A;
  const char* gB = (const char*)Bt;
  const size_t gA0 = ((size_t)(m0 + srow) * K) * 2 + scolb;
  const size_t gA1 = ((size_t)(m0 + 64 + srow) * K) * 2 + scolb;
  const size_t gB0 = ((size_t)(n0 + srow) * K) * 2 + scolb;
  const size_t gB1 = ((size_t)(n0 + 64 + srow) * K) * 2 + scolb;
  bf16* lA0 = &As[w * 512];
  bf16* lA1 = &As[2048 + w * 512];
  bf16* lB0 = &Bs[w * 512];
  bf16* lB1 = &Bs[2048 + w * 512];

  const bf16* pA = &As[(wm * 64 + l15) * 32 + 8 * g];
  const bf16* pB = &Bs[(wn * 64 + l15) * 32 + 8 * g];

  for (int k0 = 0; k0 < K; k0 += 32) {
    const size_t kb = (size_t)k0 * 2;
    GLOAD_LDS(gA + gA0 + kb, lA0);
    GLOAD_LDS(gA + gA1 + kb, lA1);
    GLOAD_LDS(gB + gB0 + kb, lB0);
    GLOAD_LDS(gB + gB1 + kb, lB1);
    __syncthreads();
    bf16x8 af[4], bfr[4];
#pragma unroll
    for (int mi = 0; mi < 4; mi++) af[mi] = *(const bf16x8*)(pA + mi * 16 * 32);
#pragma unroll
    for (int ni = 0; ni < 4; ni++) bfr[ni] = *(const bf16x8*)(pB + ni * 16 * 32);
#pragma unroll
    for (int mi = 0; mi < 4; mi++)
#pragma unroll
      for (int ni = 0; ni < 4; ni++)
        acc[mi][ni] = MFMA_BF16(af[mi], bfr[ni], acc[mi][ni], 0, 0, 0);
    __syncthreads();
  }

  const int row_base = m0 + wm * 64;
  const int col_base = n0 + wn * 64 + l15;
#pragma unroll
  for (int mi = 0; mi < 4; mi++)
#pragma unroll
    for (int ni = 0; ni < 4; ni++) {
      const int c = col_base + ni * 16;
#pragma unroll
      for (int r = 0; r < 4; r++) {
        const int row = row_base + mi * 16 + 4 * g + r;
        const size_t idx = (size_t)row * N + c;
        float v = acc[mi][ni][r];
        if constexpr (MODE == 0) {
          outb[idx] = (bf16)v;
        } else if constexpr (MODE == 1) {
          float xv = v + resid[idx];
          outf[idx] = xv;
          outb[idx] = (bf16)xv;
        } else if constexpr (MODE == 2) {
          outb[idx] = (bf16)gelu_exact(v);
        } else {
          outf[idx] = v + resid[idx];
        }
      }
    }
}

// ---------------------------------------------------------------- attention
// qkv: [B*T][3072] bf16; O: [B*T][1024] bf16.
// 512 threads = 8 waves; wave w owns q-rows [q0+16w, q0+16w+16). BQ=128.
// Block (bh, bx) processes q-tiles bx and 15-bx -> 34 KV-steps, uniform.
// K and V^T staged in LDS (double-buffered), single barrier/step, register
// prefetch of next tile. Waves 0-3 stage V^T (4x4 reg transpose), waves 4-7
// stage K (coalesced b128, XOR-swizzled slots). QK^T reads K fragments from
// LDS with permuted rows so P lands directly in the PV B-frag layout.
__global__ __launch_bounds__(512, 2) void attn_fwd(const bf16* __restrict__ qkv,
                                                   bf16* __restrict__ O) {
  __shared__ __align__(16) char Kl[2][64 * 128];  // K tile [64 k][64 d], swizzled
  __shared__ __align__(16) char Vt[2][64 * 128];  // V^T tile [64 d][64 k], swizzled
  const int tid = threadIdx.x;
  const int lane = tid & 63, w = tid >> 6;
  const int g = lane >> 4, l15 = lane & 15;
  const int bh = blockIdx.x;
  const int bx = blockIdx.y;
  const int b = bh >> 4, hh = bh & 15;
  const size_t tokbase = (size_t)b * 2048;

  const bf16* kbase = qkv + tokbase * 3072 + 1024 + hh * 64;
  const bf16* vbase = qkv + tokbase * 3072 + 2048 + hh * 64;
  const int kperm = 8 * (l15 >> 2) + (l15 & 3);

  const bool vstage = tid < 256;
  const int t2 = tid & 255;
  // V role: rows 4*(t2>>4)+i4, d cols (t2&15)*4 ; K role: row t2>>2, slot t2&3
  const int vrg = t2 >> 4, vds = (t2 & 15) * 4;
  const int krow = t2 >> 2, ksl = t2 & 3;
  const int kswzr = (krow & 3) | ((krow & 8) >> 1);

  union U4 { ushort4 v; u16 a[4]; };
  U4 vr[4];
  uint4 kpr0, kpr1;

  auto prefetch = [&](int k0n) {
    if (vstage) {
#pragma unroll
      for (int i4 = 0; i4 < 4; i4++)
        vr[i4].v = *(const ushort4*)(vbase + (size_t)(k0n + 4 * vrg + i4) * 3072 + vds);
    } else {
      const bf16* kp = kbase + (size_t)(k0n + krow) * 3072 + 8 * ksl;
      kpr0 = *(const uint4*)(kp);
      kpr1 = *(const uint4*)(kp + 32);
    }
  };

  prefetch(0);
  int cur = 0;

  for (int half = 0; half < 2; half++) {
    const int xT = half ? (15 - bx) : bx;
    const int q0 = xT * 128;
    const int qw0 = q0 + 16 * w;
    const int qi = qw0 + l15;
    const int kend = q0 + 128;

    const bf16* qptr = qkv + (tokbase + qw0 + l15) * 3072 + hh * 64 + 8 * g;
    const bf16x8 qf0 = *(const bf16x8*)(qptr);
    const bf16x8 qf1 = *(const bf16x8*)(qptr + 32);

    f32x4 ot[4] = {};
    float m_i = -INFINITY, l_i = 0.0f;

    for (int k0 = 0; k0 < kend; k0 += 64) {
      char* Kc = Kl[cur];
      char* Vc = Vt[cur];
      // ---- write prefetched regs -> LDS
      if (vstage) {
#pragma unroll
        for (int dj = 0; dj < 4; dj++) {
          const int d = vds + dj;
          u32 lo = (u32)vr[0].a[dj] | ((u32)vr[1].a[dj] << 16);
          u32 hi = (u32)vr[2].a[dj] | ((u32)vr[3].a[dj] << 16);
          const int boff = d * 128 + ((((vrg >> 1) ^ ((d >> 1) & 7)) << 4)) + ((vrg & 1) << 3);
          *(uint2*)(Vc + boff) = make_uint2(lo, hi);
        }
      } else {
        *(uint4*)(Kc + krow * 128 + ((ksl ^ kswzr) << 4)) = kpr0;
        *(uint4*)(Kc + krow * 128 + (((ksl | 4) ^ kswzr) << 4)) = kpr1;
      }
      __syncthreads();  // single barrier per step (dbuf)

      // ---- issue next step's loads (hidden under compute)
      const int k0n = (k0 + 64 < kend) ? k0 + 64 : 0;
      prefetch(k0n);

      if (k0 <= qw0 + 15) {  // wave-uniform causal skip
        const bool lastT = (k0 + 63 > qw0);
        const int npair = lastT ? (((qw0 + 15 - k0) >> 5) + 1) : 2;

        // ---- QK^T from LDS (permuted K rows)
        f32x4 st[4];
#pragma unroll
        for (int ip = 0; ip < 2; ip++)
          if (ip < npair) {
#pragma unroll
            for (int h2 = 0; h2 < 2; h2++) {
              const int kr = 32 * ip + 4 * h2 + kperm;
              const int swzk = (kr & 3) | ((kr & 8) >> 1);
              const char* kro = Kc + kr * 128;
              bf16x8 ka = *(const bf16x8*)(kro + ((g ^ swzk) << 4));
              bf16x8 kb = *(const bf16x8*)(kro + (((g | 4) ^ swzk) << 4));
              f32x4 z = {};
              z = MFMA_BF16(ka, qf0, z, 0, 0, 0);
              st[2 * ip + h2] = MFMA_BF16(kb, qf1, z, 0, 0, 0);
            }
          }

        // ---- softmax: lane holds k = k0 + 32*ip + 8g + 4*h2 + r, col q=l15
        float p[4][4];
        float mt = -INFINITY;
#pragma unroll
        for (int ip = 0; ip < 2; ip++)
          if (ip < npair) {
#pragma unroll
            for (int h2 = 0; h2 < 2; h2++)
#pragma unroll
              for (int r = 0; r < 4; r++) {
                const int kk = k0 + 32 * ip + 8 * g + 4 * h2 + r;
                float v = (float)st[2 * ip + h2][r] * 0.125f;
                if (lastT && kk > qi) v = -INFINITY;
                p[2 * ip + h2][r] = v;
                mt = fmaxf(mt, v);
              }
          }
        mt = fmaxf(mt, __shfl_xor(mt, 16, 64));
        mt = fmaxf(mt, __shfl_xor(mt, 32, 64));

        if (!__all(mt - m_i <= 8.0f)) {  // defer-max (T13)
          const float m_new = fmaxf(m_i, mt);
          const float alpha = __expf(m_i - m_new);
          l_i *= alpha;
#pragma unroll
          for (int dt = 0; dt < 4; dt++)
#pragma unroll
            for (int r = 0; r < 4; r++) ot[dt][r] *= alpha;
          m_i = m_new;
        }
        float s = 0.0f;
#pragma unroll
        for (int ip = 0; ip < 2; ip++)
          if (ip < npair) {
#pragma unroll
            for (int h2 = 0; h2 < 2; h2++)
#pragma unroll
              for (int r = 0; r < 4; r++) {
                float e = __expf(p[2 * ip + h2][r] - m_i);
                p[2 * ip + h2][r] = e;
                s += e;
              }
          }
        s += __shfl_xor(s, 16, 64);
        s += __shfl_xor(s, 32, 64);
        l_i += s;

        // ---- PV: O^T += V^T * P^T
#pragma unroll
        for (int ip = 0; ip < 2; ip++)
          if (ip < npair) {
            bf16x8 pf;
#pragma unroll
            for (int h2 = 0; h2 < 2; h2++)
#pragma unroll
              for (int r = 0; r < 4; r++) pf[4 * h2 + r] = (bf16)p[2 * ip + h2][r];
#pragma unroll
            for (int dt = 0; dt < 4; dt++) {
              const bf16x8 vf = *(const bf16x8*)(
                  Vc + (dt * 16 + l15) * 128 + (((4 * ip + g) ^ (l15 >> 1)) << 4));
              ot[dt] = MFMA_BF16(vf, pf, ot[dt], 0, 0, 0);
            }
          }
      }
      cur ^= 1;
    }

    const float inv = 1.0f / l_i;
    bf16* obase = O + (tokbase + qw0 + l15) * 1024 + hh * 64;
#pragma unroll
    for (int dt = 0; dt < 4; dt++) {
      bf16x4 ov;
#pragma unroll
      for (int r = 0; r < 4; r++) ov[r] = (bf16)(ot[dt][r] * inv);
      *(bf16x4*)(obase + dt * 16 + 4 * g) = ov;
    }
  }
}

// ---------------------------------------------------------------- launch
extern "C" void kernel_launch(void* const* d_in, const int* in_sizes, int n_in,
                              void* d_out, int out_size, void* d_ws, size_t ws_size,
                              hipStream_t stream) {
  const float* x = (const float*)d_in[0];
  const float* w_qkv = (const float*)d_in[1];
  const float* w_out = (const float*)d_in[2];
  const float* w_ff1 = (const float*)d_in[3];
  const float* w_ff2 = (const float*)d_in[4];
  float* out = (float*)d_out;

  char* ws = (char*)d_ws;
  size_t off = 0;
  auto alloc = [&](size_t bytes) {
    void* p = ws + off;
    off += (bytes + 255) & ~(size_t)255;
    return p;
  };
  const size_t M = 8192;
  bf16* X16   = (bf16*)alloc(M * 1024 * 2);
  bf16* WqkvT = (bf16*)alloc(3072ull * 1024 * 2);
  bf16* WoutT = (bf16*)alloc(1024ull * 1024 * 2);
  bf16* Wff1T = (bf16*)alloc(4096ull * 1024 * 2);
  bf16* Wff2T = (bf16*)alloc(1024ull * 4096 * 2);
  bf16* QKV   = (bf16*)alloc(M * 3072 * 2);
  bf16* Obuf  = (bf16*)alloc(M * 1024 * 2);
  float* x1   = (float*)alloc(M * 1024 * 4);
  bf16* x1b   = (bf16*)alloc(M * 1024 * 2);
  bf16* Hbuf  = (bf16*)alloc(M * 4096 * 2);

  cvt_f32_bf16<<<8192, 256, 0, stream>>>(x, X16, 8192 * 1024);
  transpose_w<<<dim3(3072 / 32, 1024 / 32), 256, 0, stream>>>(w_qkv, WqkvT, 1024, 3072);
  transpose_w<<<dim3(1024 / 32, 1024 / 32), 256, 0, stream>>>(w_out, WoutT, 1024, 1024);
  transpose_w<<<dim3(4096 / 32, 1024 / 32), 256, 0, stream>>>(w_ff1, Wff1T, 1024, 4096);
  transpose_w<<<dim3(1024 / 32, 4096 / 32), 256, 0, stream>>>(w_ff2, Wff2T, 4096, 1024);

  gemm_bt<0><<<dim3(3072 / 128, 8192 / 128), 256, 0, stream>>>(
      X16, WqkvT, QKV, nullptr, nullptr, 1024, 3072);
  attn_fwd<<<dim3(64, 8), 512, 0, stream>>>(QKV, Obuf);
  gemm_bt<1><<<dim3(1024 / 128, 8192 / 128), 256, 0, stream>>>(
      Obuf, WoutT, x1b, x1, x, 1024, 1024);
  gemm_bt<2><<<dim3(4096 / 128, 8192 / 128), 256, 0, stream>>>(
      x1b, Wff1T, Hbuf, nullptr, nullptr, 1024, 4096);
  gemm_bt<3><<<dim3(1024 / 128, 8192 / 128), 256, 0, stream>>>(
      Hbuf, Wff2T, nullptr, out, x1, 4096, 1024);
}

// Round 5
// 419.878 us; speedup vs baseline: 1.5666x; 1.0501x over previous
//
#include <hip/hip_runtime.h>

typedef __bf16 bf16;
typedef __bf16 bf16x8 __attribute__((ext_vector_type(8)));
typedef __bf16 bf16x4 __attribute__((ext_vector_type(4)));
typedef float f32x4 __attribute__((ext_vector_type(4)));
typedef unsigned int u32;
typedef unsigned short u16;

#define MFMA_BF16 __builtin_amdgcn_mfma_f32_16x16x32_bf16

#define GLOAD_LDS(g, l)                                        \
  __builtin_amdgcn_global_load_lds(                            \
      (__attribute__((address_space(1))) void*)(g),            \
      (__attribute__((address_space(3))) void*)(l), 16, 0, 0)

// ---------------------------------------------------------------- utilities
__global__ void cvt_f32_bf16(const float* __restrict__ in, bf16* __restrict__ out, int n) {
  int i = (blockIdx.x * blockDim.x + threadIdx.x) * 4;
  if (i >= n) return;
  float4 v = *(const float4*)(in + i);
  bf16x4 o;
  o[0] = (bf16)v.x; o[1] = (bf16)v.y; o[2] = (bf16)v.z; o[3] = (bf16)v.w;
  *(bf16x4*)(out + i) = o;
}

// W [K][N] fp32 -> Wt [N][K] bf16
__global__ void transpose_w(const float* __restrict__ w, bf16* __restrict__ wt, int K, int N) {
  __shared__ float tile[32][33];
  int n0 = blockIdx.x * 32, k0 = blockIdx.y * 32;
  int t = threadIdx.x;
  int c = t & 31, r = t >> 5;
#pragma unroll
  for (int i = 0; i < 4; i++)
    tile[r + i * 8][c] = w[(size_t)(k0 + r + i * 8) * N + n0 + c];
  __syncthreads();
#pragma unroll
  for (int i = 0; i < 4; i++)
    wt[(size_t)(n0 + r + i * 8) * K + k0 + c] = (bf16)tile[c][r + i * 8];
}

__device__ inline float gelu_exact(float x) {
  return 0.5f * x * (1.0f + erff(x * 0.70710678118654752f));
}

// ---------------------------------------------------------------- GEMM
// C[M][N] = A[M][K] * Bt[N][K]^T, M=8192, 128x128 tile, BK=32, 4 waves.
// Ring-3 LDS staging, counted vmcnt(4) (never 0 in loop), one raw s_barrier
// per K-step. LDS reads 2-way-free via XOR swizzle (chunk ^= (row>>1)&3),
// applied on the READ side + pre-swizzled GLOBAL source (linear LDS dest).
// 1-D grid, XCD-chunked M-fastest order: xcd = bid&7 owns a contiguous
// N-tile span; B col-panels stay L2-resident, A streams via L3.
template <int MODE>
__global__ __launch_bounds__(256, 3) void gemm_bt(
    const bf16* __restrict__ A, const bf16* __restrict__ Bt,
    bf16* __restrict__ outb, float* __restrict__ outf,
    const float* __restrict__ resid, int K, int N) {
  __shared__ __align__(16) bf16 As[3][128 * 32];
  __shared__ __align__(16) bf16 Bs[3][128 * 32];
  const int tid = threadIdx.x;
  const int lane = tid & 63, w = tid >> 6;
  const int g = lane >> 4, l15 = lane & 15;

  // XCD-chunked mapping (nwg always multiple of 8; M-tiles = 64)
  const int cpx = gridDim.x >> 3;
  const int widx = (blockIdx.x & 7) * cpx + (blockIdx.x >> 3);
  const int m0 = (widx & 63) * 128, n0 = (widx >> 6) * 128;
  const int wm = w >> 1, wn = w & 1;

  f32x4 acc[4][4] = {};

  // staging: wave w covers rows i*64 + w*16 + lane/4; 16B chunk pre-swizzled
  const int srow = w * 16 + (lane >> 2);
  const int schunk = (lane & 3) ^ ((lane >> 3) & 3);
  const int scolb = schunk * 16;
  const char* gA = (const char*)A;
  const char* gB = (const char*)Bt;
  const size_t gA0 = ((size_t)(m0 + srow) * K) * 2 + scolb;
  const size_t gA1 = ((size_t)(m0 + 64 + srow) * K) * 2 + scolb;
  const size_t gB0 = ((size_t)(n0 + srow) * K) * 2 + scolb;
  const size_t gB1 = ((size_t)(n0 + 64 + srow) * K) * 2 + scolb;

  auto stage = [&](int kt, int c) {
    const size_t kb = (size_t)kt * 64;  // kt*32 elems * 2B
    GLOAD_LDS(gA + gA0 + kb, &As[c][w * 512]);
    GLOAD_LDS(gA + gA1 + kb, &As[c][2048 + w * 512]);
    GLOAD_LDS(gB + gB0 + kb, &Bs[c][w * 512]);
    GLOAD_LDS(gB + gB1 + kb, &Bs[c][2048 + w * 512]);
  };

  // read offsets (bytes): row*64 + swizzled 16B chunk
  const int rsw = (g ^ ((l15 >> 1) & 3)) << 4;
  const int rdA = (wm * 64 + l15) * 64 + rsw;
  const int rdB = (wn * 64 + l15) * 64 + rsw;

  const int T = K >> 5;
  stage(0, 0);
  stage(1, 1);

  int cur = 0;
  for (int t = 0; t < T; ++t) {
    if (t < T - 1) asm volatile("s_waitcnt vmcnt(4)" ::: "memory");
    else          asm volatile("s_waitcnt vmcnt(0)" ::: "memory");
    asm volatile("s_waitcnt lgkmcnt(0)" ::: "memory");
    __builtin_amdgcn_s_barrier();
    __builtin_amdgcn_sched_barrier(0);
    if (t + 2 < T) {
      int c2 = cur + 2; if (c2 >= 3) c2 -= 3;
      stage(t + 2, c2);
    }
    const char* pA = (const char*)As[cur];
    const char* pB = (const char*)Bs[cur];
    bf16x8 af[4], bfr[4];
#pragma unroll
    for (int mi = 0; mi < 4; mi++) af[mi] = *(const bf16x8*)(pA + rdA + mi * 1024);
#pragma unroll
    for (int ni = 0; ni < 4; ni++) bfr[ni] = *(const bf16x8*)(pB + rdB + ni * 1024);
#pragma unroll
    for (int mi = 0; mi < 4; mi++)
#pragma unroll
      for (int ni = 0; ni < 4; ni++)
        acc[mi][ni] = MFMA_BF16(af[mi], bfr[ni], acc[mi][ni], 0, 0, 0);
    cur += 1; if (cur >= 3) cur -= 3;
  }

  const int row_base = m0 + wm * 64;
  const int col_base = n0 + wn * 64 + l15;
#pragma unroll
  for (int mi = 0; mi < 4; mi++)
#pragma unroll
    for (int ni = 0; ni < 4; ni++) {
      const int c = col_base + ni * 16;
#pragma unroll
      for (int r = 0; r < 4; r++) {
        const int row = row_base + mi * 16 + 4 * g + r;
        const size_t idx = (size_t)row * N + c;
        float v = acc[mi][ni][r];
        if constexpr (MODE == 0) {
          outb[idx] = (bf16)v;
        } else if constexpr (MODE == 1) {
          float xv = v + resid[idx];
          outf[idx] = xv;
          outb[idx] = (bf16)xv;
        } else if constexpr (MODE == 2) {
          outb[idx] = (bf16)gelu_exact(v);
        } else {
          outf[idx] = v + resid[idx];
        }
      }
    }
}

// ---------------------------------------------------------------- attention
// (unchanged from R4: 512 thr, BQ=128, paired q-tiles, K+V^T in LDS dbuf,
//  single barrier/step, register prefetch, permuted-K QK^T)
__global__ __launch_bounds__(512, 2) void attn_fwd(const bf16* __restrict__ qkv,
                                                   bf16* __restrict__ O) {
  __shared__ __align__(16) char Kl[2][64 * 128];
  __shared__ __align__(16) char Vt[2][64 * 128];
  const int tid = threadIdx.x;
  const int lane = tid & 63, w = tid >> 6;
  const int g = lane >> 4, l15 = lane & 15;
  const int bh = blockIdx.x;
  const int bx = blockIdx.y;
  const int b = bh >> 4, hh = bh & 15;
  const size_t tokbase = (size_t)b * 2048;

  const bf16* kbase = qkv + tokbase * 3072 + 1024 + hh * 64;
  const bf16* vbase = qkv + tokbase * 3072 + 2048 + hh * 64;
  const int kperm = 8 * (l15 >> 2) + (l15 & 3);

  const bool vstage = tid < 256;
  const int t2 = tid & 255;
  const int vrg = t2 >> 4, vds = (t2 & 15) * 4;
  const int krow = t2 >> 2, ksl = t2 & 3;
  const int kswzr = (krow & 3) | ((krow & 8) >> 1);

  union U4 { ushort4 v; u16 a[4]; };
  U4 vr[4];
  uint4 kpr0, kpr1;

  auto prefetch = [&](int k0n) {
    if (vstage) {
#pragma unroll
      for (int i4 = 0; i4 < 4; i4++)
        vr[i4].v = *(const ushort4*)(vbase + (size_t)(k0n + 4 * vrg + i4) * 3072 + vds);
    } else {
      const bf16* kp = kbase + (size_t)(k0n + krow) * 3072 + 8 * ksl;
      kpr0 = *(const uint4*)(kp);
      kpr1 = *(const uint4*)(kp + 32);
    }
  };

  prefetch(0);
  int cur = 0;

  for (int half = 0; half < 2; half++) {
    const int xT = half ? (15 - bx) : bx;
    const int q0 = xT * 128;
    const int qw0 = q0 + 16 * w;
    const int qi = qw0 + l15;
    const int kend = q0 + 128;

    const bf16* qptr = qkv + (tokbase + qw0 + l15) * 3072 + hh * 64 + 8 * g;
    const bf16x8 qf0 = *(const bf16x8*)(qptr);
    const bf16x8 qf1 = *(const bf16x8*)(qptr + 32);

    f32x4 ot[4] = {};
    float m_i = -INFINITY, l_i = 0.0f;

    for (int k0 = 0; k0 < kend; k0 += 64) {
      char* Kc = Kl[cur];
      char* Vc = Vt[cur];
      if (vstage) {
#pragma unroll
        for (int dj = 0; dj < 4; dj++) {
          const int d = vds + dj;
          u32 lo = (u32)vr[0].a[dj] | ((u32)vr[1].a[dj] << 16);
          u32 hi = (u32)vr[2].a[dj] | ((u32)vr[3].a[dj] << 16);
          const int boff = d * 128 + ((((vrg >> 1) ^ ((d >> 1) & 7)) << 4)) + ((vrg & 1) << 3);
          *(uint2*)(Vc + boff) = make_uint2(lo, hi);
        }
      } else {
        *(uint4*)(Kc + krow * 128 + ((ksl ^ kswzr) << 4)) = kpr0;
        *(uint4*)(Kc + krow * 128 + (((ksl | 4) ^ kswzr) << 4)) = kpr1;
      }
      __syncthreads();

      const int k0n = (k0 + 64 < kend) ? k0 + 64 : 0;
      prefetch(k0n);

      if (k0 <= qw0 + 15) {
        const bool lastT = (k0 + 63 > qw0);
        const int npair = lastT ? (((qw0 + 15 - k0) >> 5) + 1) : 2;

        f32x4 st[4];
#pragma unroll
        for (int ip = 0; ip < 2; ip++)
          if (ip < npair) {
#pragma unroll
            for (int h2 = 0; h2 < 2; h2++) {
              const int kr = 32 * ip + 4 * h2 + kperm;
              const int swzk = (kr & 3) | ((kr & 8) >> 1);
              const char* kro = Kc + kr * 128;
              bf16x8 ka = *(const bf16x8*)(kro + ((g ^ swzk) << 4));
              bf16x8 kb = *(const bf16x8*)(kro + (((g | 4) ^ swzk) << 4));
              f32x4 z = {};
              z = MFMA_BF16(ka, qf0, z, 0, 0, 0);
              st[2 * ip + h2] = MFMA_BF16(kb, qf1, z, 0, 0, 0);
            }
          }

        float p[4][4];
        float mt = -INFINITY;
#pragma unroll
        for (int ip = 0; ip < 2; ip++)
          if (ip < npair) {
#pragma unroll
            for (int h2 = 0; h2 < 2; h2++)
#pragma unroll
              for (int r = 0; r < 4; r++) {
                const int kk = k0 + 32 * ip + 8 * g + 4 * h2 + r;
                float v = (float)st[2 * ip + h2][r] * 0.125f;
                if (lastT && kk > qi) v = -INFINITY;
                p[2 * ip + h2][r] = v;
                mt = fmaxf(mt, v);
              }
          }
        mt = fmaxf(mt, __shfl_xor(mt, 16, 64));
        mt = fmaxf(mt, __shfl_xor(mt, 32, 64));

        if (!__all(mt - m_i <= 8.0f)) {
          const float m_new = fmaxf(m_i, mt);
          const float alpha = __expf(m_i - m_new);
          l_i *= alpha;
#pragma unroll
          for (int dt = 0; dt < 4; dt++)
#pragma unroll
            for (int r = 0; r < 4; r++) ot[dt][r] *= alpha;
          m_i = m_new;
        }
        float s = 0.0f;
#pragma unroll
        for (int ip = 0; ip < 2; ip++)
          if (ip < npair) {
#pragma unroll
            for (int h2 = 0; h2 < 2; h2++)
#pragma unroll
              for (int r = 0; r < 4; r++) {
                float e = __expf(p[2 * ip + h2][r] - m_i);
                p[2 * ip + h2][r] = e;
                s += e;
              }
          }
        s += __shfl_xor(s, 16, 64);
        s += __shfl_xor(s, 32, 64);
        l_i += s;

#pragma unroll
        for (int ip = 0; ip < 2; ip++)
          if (ip < npair) {
            bf16x8 pf;
#pragma unroll
            for (int h2 = 0; h2 < 2; h2++)
#pragma unroll
              for (int r = 0; r < 4; r++) pf[4 * h2 + r] = (bf16)p[2 * ip + h2][r];
#pragma unroll
            for (int dt = 0; dt < 4; dt++) {
              const bf16x8 vf = *(const bf16x8*)(
                  Vc + (dt * 16 + l15) * 128 + (((4 * ip + g) ^ (l15 >> 1)) << 4));
              ot[dt] = MFMA_BF16(vf, pf, ot[dt], 0, 0, 0);
            }
          }
      }
      cur ^= 1;
    }

    const float inv = 1.0f / l_i;
    bf16* obase = O + (tokbase + qw0 + l15) * 1024 + hh * 64;
#pragma unroll
    for (int dt = 0; dt < 4; dt++) {
      bf16x4 ov;
#pragma unroll
      for (int r = 0; r < 4; r++) ov[r] = (bf16)(ot[dt][r] * inv);
      *(bf16x4*)(obase + dt * 16 + 4 * g) = ov;
    }
  }
}

// ---------------------------------------------------------------- launch
extern "C" void kernel_launch(void* const* d_in, const int* in_sizes, int n_in,
                              void* d_out, int out_size, void* d_ws, size_t ws_size,
                              hipStream_t stream) {
  const float* x = (const float*)d_in[0];
  const float* w_qkv = (const float*)d_in[1];
  const float* w_out = (const float*)d_in[2];
  const float* w_ff1 = (const float*)d_in[3];
  const float* w_ff2 = (const float*)d_in[4];
  float* out = (float*)d_out;

  char* ws = (char*)d_ws;
  size_t off = 0;
  auto alloc = [&](size_t bytes) {
    void* p = ws + off;
    off += (bytes + 255) & ~(size_t)255;
    return p;
  };
  const size_t M = 8192;
  bf16* X16   = (bf16*)alloc(M * 1024 * 2);
  bf16* WqkvT = (bf16*)alloc(3072ull * 1024 * 2);
  bf16* WoutT = (bf16*)alloc(1024ull * 1024 * 2);
  bf16* Wff1T = (bf16*)alloc(4096ull * 1024 * 2);
  bf16* Wff2T = (bf16*)alloc(1024ull * 4096 * 2);
  bf16* QKV   = (bf16*)alloc(M * 3072 * 2);
  bf16* Obuf  = (bf16*)alloc(M * 1024 * 2);
  float* x1   = (float*)alloc(M * 1024 * 4);
  bf16* x1b   = (bf16*)alloc(M * 1024 * 2);
  bf16* Hbuf  = (bf16*)alloc(M * 4096 * 2);

  cvt_f32_bf16<<<8192, 256, 0, stream>>>(x, X16, 8192 * 1024);
  transpose_w<<<dim3(3072 / 32, 1024 / 32), 256, 0, stream>>>(w_qkv, WqkvT, 1024, 3072);
  transpose_w<<<dim3(1024 / 32, 1024 / 32), 256, 0, stream>>>(w_out, WoutT, 1024, 1024);
  transpose_w<<<dim3(4096 / 32, 1024 / 32), 256, 0, stream>>>(w_ff1, Wff1T, 1024, 4096);
  transpose_w<<<dim3(1024 / 32, 4096 / 32), 256, 0, stream>>>(w_ff2, Wff2T, 4096, 1024);

  // 1-D grids: nwg = (N/128)*(M/128), M-tiles=64 fastest inside XCD chunks
  gemm_bt<0><<<24 * 64, 256, 0, stream>>>(X16, WqkvT, QKV, nullptr, nullptr, 1024, 3072);
  attn_fwd<<<dim3(64, 8), 512, 0, stream>>>(QKV, Obuf);
  gemm_bt<1><<<8 * 64, 256, 0, stream>>>(Obuf, WoutT, x1b, x1, x, 1024, 1024);
  gemm_bt<2><<<32 * 64, 256, 0, stream>>>(x1b, Wff1T, Hbuf, nullptr, nullptr, 1024, 4096);
  gemm_bt<3><<<8 * 64, 256, 0, stream>>>(Hbuf, Wff2T, nullptr, out, x1, 4096, 1024);
}